// Round 3
// baseline (503.351 us; speedup 1.0000x reference)
//
#include <hip/hip_runtime.h>
#include <hip/hip_bf16.h>
#include <math.h>

constexpr int Dm = 1024;
constexpr int Hh = 16;
constexpr int Ff = 4096;
constexpr int Ss = 512;
constexpr int Bbatch = 16;
constexpr int NT = Bbatch * Ss;   // 8192 tokens
constexpr float EPSc = 1e-5f;

typedef __attribute__((ext_vector_type(8))) short bfrag;   // 8 bf16 (4 VGPR)
typedef __attribute__((ext_vector_type(4))) float f32x4;

static __device__ __forceinline__ float gelu_f(float v) {
    return 0.5f * v * (1.0f + erff(v * 0.70710678118654752f));
}

static __device__ __forceinline__ void gload16(const void* g, void* l) {
    __builtin_amdgcn_global_load_lds((__attribute__((address_space(1))) void*)g,
                                     (__attribute__((address_space(3))) void*)l,
                                     16, 0, 0);
}

// XOR swizzle for [rows][128B-row] LDS tiles (G4): byte ^= ((row&7)<<4)
#define SWZ(row, colb) ((row) * 128 + ((colb) ^ (((row) & 7) << 4)))

// ---------------- transpose + fp32->bf16 convert: in [R][C] -> out [C][R] ---
__global__ void __launch_bounds__(256) transpose_cvt(const float* __restrict__ in,
                                                     __hip_bfloat16* __restrict__ out,
                                                     int R, int C,
                                                     long in_zs, long out_zs) {
    __shared__ float tile[32][33];
    const float* inz = in + (size_t)blockIdx.z * in_zs;
    __hip_bfloat16* outz = out + (size_t)blockIdx.z * out_zs;
    const int c0 = blockIdx.x * 32, r0 = blockIdx.y * 32;
    const int tx = threadIdx.x & 31, ty4 = (threadIdx.x >> 5) * 4;
    #pragma unroll
    for (int i = 0; i < 4; i++)
        tile[ty4 + i][tx] = inz[(size_t)(r0 + ty4 + i) * C + c0 + tx];
    __syncthreads();
    #pragma unroll
    for (int i = 0; i < 4; i++)
        outz[(size_t)(c0 + ty4 + i) * R + r0 + tx] = __float2bfloat16(tile[tx][ty4 + i]);
}

// ---------------- LayerNorm fp32 in -> bf16 out ----------------------------
__global__ void __launch_bounds__(256) ln_bf16(const float* __restrict__ x,
                                               const float* __restrict__ gamma,
                                               const float* __restrict__ beta,
                                               __hip_bfloat16* __restrict__ out) {
    const int row = blockIdx.x;
    const int tid = threadIdx.x;
    const int lane = tid & 63, w = tid >> 6;
    float4 xv = reinterpret_cast<const float4*>(x + (size_t)row * Dm)[tid];
    float s  = xv.x + xv.y + xv.z + xv.w;
    float ss = xv.x * xv.x + xv.y * xv.y + xv.z * xv.z + xv.w * xv.w;
    #pragma unroll
    for (int o = 32; o > 0; o >>= 1) {
        s  += __shfl_down(s,  o, 64);
        ss += __shfl_down(ss, o, 64);
    }
    __shared__ float red[2][4];
    if (lane == 0) { red[0][w] = s; red[1][w] = ss; }
    __syncthreads();
    float st  = red[0][0] + red[0][1] + red[0][2] + red[0][3];
    float sst = red[1][0] + red[1][1] + red[1][2] + red[1][3];
    float mean = st * (1.0f / Dm);
    float var  = sst * (1.0f / Dm) - mean * mean;
    float inv  = rsqrtf(var + EPSc);
    float4 g = reinterpret_cast<const float4*>(gamma)[tid];
    float4 b = reinterpret_cast<const float4*>(beta)[tid];
    __hip_bfloat16 t[4] __attribute__((aligned(8)));
    t[0] = __float2bfloat16((xv.x - mean) * inv * g.x + b.x);
    t[1] = __float2bfloat16((xv.y - mean) * inv * g.y + b.y);
    t[2] = __float2bfloat16((xv.z - mean) * inv * g.z + b.z);
    t[3] = __float2bfloat16((xv.w - mean) * inv * g.w + b.w);
    *reinterpret_cast<ushort4*>(out + (size_t)row * Dm + tid * 4) =
        *reinterpret_cast<ushort4*>(t);
}

// ---------------- bf16 MFMA GEMM, 256xBN tile, BK=64, 8 waves, dbuf+counted vmcnt
// C = A[M,K] x Bt[N,K]^T. Swizzled LDS (both-sides: pre-swizzled global src +
// swizzled ds_read). Raw s_barrier, vmcnt(G) counted (never 0 mid-loop), setprio.
// EPI 0: bf16 C                EPI 1: f32 C = acc + bias + res
// EPI 2: bf16 C = gelu(acc+b)  EPI 3: f32 C += acc + bias
template<int BN_, int EPI>
__global__ void __launch_bounds__(512) gemm8(const __hip_bfloat16* __restrict__ A, int lda,
                                             const __hip_bfloat16* __restrict__ Bt, int ldb,
                                             const float* __restrict__ bias,
                                             const float* __restrict__ res,
                                             void* __restrict__ Cout, int ldc,
                                             int nbx, int K) {
    constexpr int NREP = BN_ / 64;           // B-frags per wave (4 or 2)
    constexpr int WNS  = BN_ / 4;            // per-wave N span
    __shared__ __hip_bfloat16 As[2][256 * 64];
    __shared__ __hip_bfloat16 Bs[2][BN_ * 64];
    const int tid = threadIdx.x, l = tid & 63, w = tid >> 6;
    const int lr = l & 15, lg = l >> 4;
    const int nwg = gridDim.x;
    const int sbid = (blockIdx.x & 7) * (nwg >> 3) + (blockIdx.x >> 3);
    const int bx = sbid % nbx, by = sbid / nbx;
    const int m0 = by * 256, n0 = bx * BN_;
    const int wr = w >> 2, wc = w & 3;
    // staging lane geometry: wave call covers 8 rows x 128B, linear LDS dest
    const int srow = l >> 3;                  // row within 8-row group
    const int scol = ((l & 7) ^ srow) * 8;    // pre-swizzled source col (elems)

    const int NK = K >> 6;
    auto STAGE = [&](int t, int bsel) {
        const int k0 = t * 64;
        #pragma unroll
        for (int j = 0; j < 4; j++) {
            const int rb = j * 64 + w * 8;
            gload16(A + (size_t)(m0 + rb + srow) * lda + k0 + scol, &As[bsel][rb * 64]);
        }
        #pragma unroll
        for (int j = 0; j < NREP; j++) {
            const int rb = j * 64 + w * 8;
            gload16(Bt + (size_t)(n0 + rb + srow) * ldb + k0 + scol, &Bs[bsel][rb * 64]);
        }
    };

    f32x4 acc[8][NREP] = {};
    STAGE(0, 0);
    STAGE(1, 1);
    for (int t = 0; t < NK; t++) {
        const int cur = t & 1;
        if (t + 1 < NK) {
            if constexpr (BN_ == 256) asm volatile("s_waitcnt vmcnt(8)" ::: "memory");
            else                      asm volatile("s_waitcnt vmcnt(6)" ::: "memory");
        } else {
            asm volatile("s_waitcnt vmcnt(0)" ::: "memory");
        }
        __builtin_amdgcn_s_barrier();
        const char* Ab = (const char*)&As[cur][0];
        const char* Bb = (const char*)&Bs[cur][0];
        #pragma unroll
        for (int kk = 0; kk < 2; kk++) {
            bfrag a[8], b[NREP];
            #pragma unroll
            for (int mi = 0; mi < 8; mi++) {
                const int row = wr * 128 + mi * 16 + lr;
                a[mi] = *(const bfrag*)(Ab + row * 128 + ((((kk << 2) + lg) ^ (row & 7)) << 4));
            }
            #pragma unroll
            for (int ni = 0; ni < NREP; ni++) {
                const int row = wc * WNS + ni * 16 + lr;
                b[ni] = *(const bfrag*)(Bb + row * 128 + ((((kk << 2) + lg) ^ (row & 7)) << 4));
            }
            __builtin_amdgcn_s_setprio(1);
            #pragma unroll
            for (int mi = 0; mi < 8; mi++)
                #pragma unroll
                for (int ni = 0; ni < NREP; ni++)
                    acc[mi][ni] = __builtin_amdgcn_mfma_f32_16x16x32_bf16(a[mi], b[ni], acc[mi][ni], 0, 0, 0);
            __builtin_amdgcn_s_setprio(0);
        }
        __builtin_amdgcn_s_barrier();
        if (t + 2 < NK) STAGE(t + 2, cur);
    }
    #pragma unroll
    for (int mi = 0; mi < 8; mi++) {
        #pragma unroll
        for (int ni = 0; ni < NREP; ni++) {
            #pragma unroll
            for (int rg = 0; rg < 4; rg++) {
                const int row = m0 + wr * 128 + mi * 16 + lg * 4 + rg;
                const int col = n0 + wc * WNS + ni * 16 + lr;
                const size_t off = (size_t)row * ldc + col;
                const float v = acc[mi][ni][rg];
                if (EPI == 0) {
                    ((__hip_bfloat16*)Cout)[off] = __float2bfloat16(v);
                } else if (EPI == 1) {
                    ((float*)Cout)[off] = v + bias[col] + res[off];
                } else if (EPI == 2) {
                    ((__hip_bfloat16*)Cout)[off] = __float2bfloat16(gelu_f(v + bias[col]));
                } else {
                    ((float*)Cout)[off] = ((float*)Cout)[off] + v + bias[col];
                }
            }
        }
    }
}

// ---------------- Flash attention, bf16 MFMA -------------------------------
// QKV [NT][3072]: Q at col 0, K at 1024, V at 2048 (+h*64). Block = (b,h,qt):
// 64 Q-rows, 4 waves x 16 rows. K/V tiles of 64 keys, online softmax.
__global__ void __launch_bounds__(256) attn_mfma(const __hip_bfloat16* __restrict__ QKV,
                                                 __hip_bfloat16* __restrict__ Oc) {
    constexpr int LDQ = 3072;
    __shared__ __hip_bfloat16 Qs[64 * 64];
    __shared__ __hip_bfloat16 Ks[64 * 64];
    __shared__ __hip_bfloat16 Vts[64 * 64];   // V^T [feat][key]
    __shared__ __hip_bfloat16 Ps[4][16 * 64]; // per-wave P
    const int tid = threadIdx.x, l = tid & 63, w = tid >> 6;
    const int lr = l & 15, lg = l >> 4;
    const int qt = blockIdx.x & 7;
    const int h  = (blockIdx.x >> 3) & 15;
    const int b  = blockIdx.x >> 7;

    const __hip_bfloat16* Qg = QKV + (size_t)(b * Ss + qt * 64) * LDQ + h * 64;
    const __hip_bfloat16* Kg = QKV + (size_t)(b * Ss) * LDQ + 1024 + h * 64;
    const __hip_bfloat16* Vg = QKV + (size_t)(b * Ss) * LDQ + 2048 + h * 64;

    const int r8 = l >> 3;                    // row-in-slot 0..7
    const int scol = 8 * ((l & 7) ^ r8);      // pre-swizzled source col (elems)

    #pragma unroll
    for (int j = 0; j < 2; j++) {
        const int slot = w * 2 + j;
        gload16(Qg + (size_t)(slot * 8 + r8) * LDQ + scol, Qs + slot * 512);
    }

    float m_run[4] = {-1e30f, -1e30f, -1e30f, -1e30f};
    float l_run[4] = {0.f, 0.f, 0.f, 0.f};
    f32x4 acc_o[4] = {};

    for (int kt = 0; kt <= qt; ++kt) {
        __syncthreads();   // prev-iter LDS reads done (iter 0: Q staged)
        #pragma unroll
        for (int j = 0; j < 2; j++) {
            const int slot = w * 2 + j;
            gload16(Kg + (size_t)(kt * 64 + slot * 8 + r8) * LDQ + scol, Ks + slot * 512);
        }
        // V^T: reg-stage with swizzled transpose writes
        unsigned short* vt = reinterpret_cast<unsigned short*>(Vts);
        #pragma unroll
        for (int j = 0; j < 2; j++) {
            const int e = tid + j * 256;
            const int key = e >> 3, f0 = (e & 7) * 8;
            const uint4 raw = *reinterpret_cast<const uint4*>(
                Vg + (size_t)(kt * 64 + key) * LDQ + f0);
            const unsigned int rw[4] = {raw.x, raw.y, raw.z, raw.w};
            #pragma unroll
            for (int e2 = 0; e2 < 8; e2++) {
                const int feat = f0 + e2;
                const int ad = feat * 128 + ((key * 2) ^ ((feat & 7) << 4));
                vt[ad >> 1] = (unsigned short)(rw[e2 >> 1] >> ((e2 & 1) * 16));
            }
        }
        __syncthreads();   // K, V^T staged

        // QK^T -> S [16 q-rows][64 keys] per wave
        f32x4 s4[4] = {};
        #pragma unroll
        for (int kk = 0; kk < 2; kk++) {
            const bfrag aq = *reinterpret_cast<const bfrag*>(
                (const char*)Qs + SWZ(w * 16 + lr, kk * 64 + lg * 16));
            #pragma unroll
            for (int ni = 0; ni < 4; ni++) {
                const bfrag bk = *reinterpret_cast<const bfrag*>(
                    (const char*)Ks + SWZ(ni * 16 + lr, kk * 64 + lg * 16));
                s4[ni] = __builtin_amdgcn_mfma_f32_16x16x32_bf16(aq, bk, s4[ni], 0, 0, 0);
            }
        }
        float p[4][4];
        #pragma unroll
        for (int ni = 0; ni < 4; ni++)
            #pragma unroll
            for (int rg = 0; rg < 4; rg++)
                p[ni][rg] = s4[ni][rg] * 0.125f;
        if (kt == qt) {   // causal mask on diagonal tile
            #pragma unroll
            for (int ni = 0; ni < 4; ni++)
                #pragma unroll
                for (int rg = 0; rg < 4; rg++)
                    if (ni * 16 + lr > w * 16 + lg * 4 + rg) p[ni][rg] = -1e30f;
        }
        float sf[4];
        #pragma unroll
        for (int rg = 0; rg < 4; rg++) {
            float mx = fmaxf(fmaxf(p[0][rg], p[1][rg]), fmaxf(p[2][rg], p[3][rg]));
            #pragma unroll
            for (int o = 1; o < 16; o <<= 1) mx = fmaxf(mx, __shfl_xor(mx, o, 64));
            const float mn = fmaxf(m_run[rg], mx);
            sf[rg] = __expf(m_run[rg] - mn);
            m_run[rg] = mn;
        }
        float rsum[4] = {};
        #pragma unroll
        for (int ni = 0; ni < 4; ni++)
            #pragma unroll
            for (int rg = 0; rg < 4; rg++) {
                const float e = __expf(p[ni][rg] - m_run[rg]);
                p[ni][rg] = e;
                rsum[rg] += e;
            }
        #pragma unroll
        for (int rg = 0; rg < 4; rg++) {
            #pragma unroll
            for (int o = 1; o < 16; o <<= 1) rsum[rg] += __shfl_xor(rsum[rg], o, 64);
            l_run[rg] = l_run[rg] * sf[rg] + rsum[rg];
        }
        #pragma unroll
        for (int di = 0; di < 4; di++)
            #pragma unroll
            for (int rg = 0; rg < 4; rg++)
                acc_o[di][rg] *= sf[rg];
        // P -> bf16 -> per-wave LDS (swizzled), then PV
        unsigned short* pw = reinterpret_cast<unsigned short*>(Ps[w]);
        #pragma unroll
        for (int ni = 0; ni < 4; ni++)
            #pragma unroll
            for (int rg = 0; rg < 4; rg++) {
                const int prow = lg * 4 + rg;
                const int ad = SWZ(prow, (ni * 16 + lr) * 2);
                __hip_bfloat16 pb = __float2bfloat16(p[ni][rg]);
                pw[ad >> 1] = *reinterpret_cast<unsigned short*>(&pb);
            }
        #pragma unroll
        for (int kk = 0; kk < 2; kk++) {
            const bfrag pa = *reinterpret_cast<const bfrag*>(
                (const char*)Ps[w] + SWZ(lr, kk * 64 + lg * 16));
            #pragma unroll
            for (int di = 0; di < 4; di++) {
                const bfrag vb = *reinterpret_cast<const bfrag*>(
                    (const char*)Vts + SWZ(di * 16 + lr, kk * 64 + lg * 16));
                acc_o[di] = __builtin_amdgcn_mfma_f32_16x16x32_bf16(pa, vb, acc_o[di], 0, 0, 0);
            }
        }
    }
    #pragma unroll
    for (int di = 0; di < 4; di++)
        #pragma unroll
        for (int rg = 0; rg < 4; rg++) {
            const int q = qt * 64 + w * 16 + lg * 4 + rg;
            const float v = acc_o[di][rg] / l_run[rg];
            Oc[(size_t)(b * Ss + q) * Dm + h * 64 + di * 16 + lr] = __float2bfloat16(v);
        }
}

extern "C" void kernel_launch(void* const* d_in, const int* in_sizes, int n_in,
                              void* d_out, int out_size, void* d_ws, size_t ws_size,
                              hipStream_t stream) {
    const float* x   = (const float*)d_in[0];
    const float* Wq  = (const float*)d_in[1];
    const float* Wk  = (const float*)d_in[2];
    const float* Wv  = (const float*)d_in[3];
    const float* Wo  = (const float*)d_in[4];
    const float* bo  = (const float*)d_in[5];
    const float* g1  = (const float*)d_in[6];
    const float* be1 = (const float*)d_in[7];
    const float* g2  = (const float*)d_in[8];
    const float* be2 = (const float*)d_in[9];
    const float* W1  = (const float*)d_in[10];
    const float* b1  = (const float*)d_in[11];
    const float* W2  = (const float*)d_in[12];
    const float* b2  = (const float*)d_in[13];
    float* out = (float*)d_out;

    // workspace (bytes): bf16 weights 24MB | n1/concat/n2 16MB | QKV 48MB, h1 64MB
    char* wsb = (char*)d_ws;
    __hip_bfloat16* WqkvT = (__hip_bfloat16*)(wsb);                 // [3072][1024]
    __hip_bfloat16* WoT   = (__hip_bfloat16*)(wsb + 6291456);       // [1024][1024]
    __hip_bfloat16* W1T   = (__hip_bfloat16*)(wsb + 8388608);       // [4096][1024]
    __hip_bfloat16* W2T   = (__hip_bfloat16*)(wsb + 16777216);      // [1024][4096]
    __hip_bfloat16* n1    = (__hip_bfloat16*)(wsb + 25165824);      // [8192][1024]
    __hip_bfloat16* QKV   = (__hip_bfloat16*)(wsb + 41943040);      // [8192][3072]
    __hip_bfloat16* concat = n1;                                    // alias (n1 dead)
    __hip_bfloat16* n2     = n1;                                    // alias (concat dead)
    __hip_bfloat16* h1     = QKV;                                   // alias (QKV dead), [8192][4096]

    // weight transpose+convert
    transpose_cvt<<<dim3(2, 32, 16), 256, 0, stream>>>(Wq, WqkvT,              1024, 64, 65536, 65536);
    transpose_cvt<<<dim3(2, 32, 16), 256, 0, stream>>>(Wk, WqkvT + 1024 * 1024, 1024, 64, 65536, 65536);
    transpose_cvt<<<dim3(2, 32, 16), 256, 0, stream>>>(Wv, WqkvT + 2048 * 1024, 1024, 64, 65536, 65536);
    transpose_cvt<<<dim3(32, 32, 1), 256, 0, stream>>>(Wo, WoT, 1024, 1024, 0, 0);
    transpose_cvt<<<dim3(128, 32, 1), 256, 0, stream>>>(W1, W1T, 1024, 4096, 0, 0);
    transpose_cvt<<<dim3(32, 128, 1), 256, 0, stream>>>(W2, W2T, 4096, 1024, 0, 0);

    ln_bf16<<<NT, 256, 0, stream>>>(x, g1, be1, n1);
    // QKV: M=8192 N=3072 K=1024, 256x256 tiles -> 12x32=384 blocks
    gemm8<256, 0><<<384, 512, 0, stream>>>(n1, Dm, WqkvT, Dm, nullptr, nullptr,
                                           QKV, 3072, 12, Dm);
    attn_mfma<<<NT * Hh / 64, 256, 0, stream>>>(QKV, concat);
    // proj: N=1024, 256x128 tiles -> 8x32=256 blocks
    gemm8<128, 1><<<256, 512, 0, stream>>>(concat, Dm, WoT, Dm, bo, x,
                                           out, Dm, 8, Dm);
    ln_bf16<<<NT, 256, 0, stream>>>(out, g2, be2, n2);
    // FFN1: N=4096, 256x256 tiles -> 16x32=512 blocks
    gemm8<256, 2><<<512, 512, 0, stream>>>(n2, Dm, W1T, Dm, b1, nullptr,
                                           h1, Ff, 16, Dm);
    // FFN2: M=8192 N=1024 K=4096, 256x128 tiles -> 256 blocks
    gemm8<128, 3><<<256, 512, 0, stream>>>(h1, Ff, W2T, Ff, b2, nullptr,
                                           out, Dm, 8, Ff);
}

// Round 4
// 480.520 us; speedup vs baseline: 1.0475x; 1.0475x over previous
//
#include <hip/hip_runtime.h>
#include <hip/hip_bf16.h>
#include <math.h>

constexpr int Dm = 1024;
constexpr int Hh = 16;
constexpr int Ff = 4096;
constexpr int Ss = 512;
constexpr int Bbatch = 16;
constexpr int NT = Bbatch * Ss;   // 8192 tokens
constexpr float EPSc = 1e-5f;

typedef __attribute__((ext_vector_type(8))) short bfrag;   // 8 bf16 (4 VGPR)
typedef __attribute__((ext_vector_type(4))) float f32x4;

static __device__ __forceinline__ float gelu_f(float v) {
    return 0.5f * v * (1.0f + erff(v * 0.70710678118654752f));
}

static __device__ __forceinline__ void gload16(const void* g, void* l) {
    __builtin_amdgcn_global_load_lds((__attribute__((address_space(1))) void*)g,
                                     (__attribute__((address_space(3))) void*)l,
                                     16, 0, 0);
}

// XOR swizzle for [rows][128B-row] LDS tiles (G4): byte ^= ((row&7)<<4)
#define SWZ(row, colb) ((row) * 128 + ((colb) ^ (((row) & 7) << 4)))

// ---------------- transpose + fp32->bf16 convert: in [R][C] -> out [C][R] ---
__global__ void __launch_bounds__(256) transpose_cvt(const float* __restrict__ in,
                                                     __hip_bfloat16* __restrict__ out,
                                                     int R, int C,
                                                     long in_zs, long out_zs) {
    __shared__ float tile[32][33];
    const float* inz = in + (size_t)blockIdx.z * in_zs;
    __hip_bfloat16* outz = out + (size_t)blockIdx.z * out_zs;
    const int c0 = blockIdx.x * 32, r0 = blockIdx.y * 32;
    const int tx = threadIdx.x & 31, ty4 = (threadIdx.x >> 5) * 4;
    #pragma unroll
    for (int i = 0; i < 4; i++)
        tile[ty4 + i][tx] = inz[(size_t)(r0 + ty4 + i) * C + c0 + tx];
    __syncthreads();
    #pragma unroll
    for (int i = 0; i < 4; i++)
        outz[(size_t)(c0 + ty4 + i) * R + r0 + tx] = __float2bfloat16(tile[tx][ty4 + i]);
}

// ---------------- LayerNorm fp32 in -> bf16 out ----------------------------
__global__ void __launch_bounds__(256) ln_bf16(const float* __restrict__ x,
                                               const float* __restrict__ gamma,
                                               const float* __restrict__ beta,
                                               __hip_bfloat16* __restrict__ out) {
    const int row = blockIdx.x;
    const int tid = threadIdx.x;
    const int lane = tid & 63, w = tid >> 6;
    float4 xv = reinterpret_cast<const float4*>(x + (size_t)row * Dm)[tid];
    float s  = xv.x + xv.y + xv.z + xv.w;
    float ss = xv.x * xv.x + xv.y * xv.y + xv.z * xv.z + xv.w * xv.w;
    #pragma unroll
    for (int o = 32; o > 0; o >>= 1) {
        s  += __shfl_down(s,  o, 64);
        ss += __shfl_down(ss, o, 64);
    }
    __shared__ float red[2][4];
    if (lane == 0) { red[0][w] = s; red[1][w] = ss; }
    __syncthreads();
    float st  = red[0][0] + red[0][1] + red[0][2] + red[0][3];
    float sst = red[1][0] + red[1][1] + red[1][2] + red[1][3];
    float mean = st * (1.0f / Dm);
    float var  = sst * (1.0f / Dm) - mean * mean;
    float inv  = rsqrtf(var + EPSc);
    float4 g = reinterpret_cast<const float4*>(gamma)[tid];
    float4 b = reinterpret_cast<const float4*>(beta)[tid];
    __hip_bfloat16 t[4] __attribute__((aligned(8)));
    t[0] = __float2bfloat16((xv.x - mean) * inv * g.x + b.x);
    t[1] = __float2bfloat16((xv.y - mean) * inv * g.y + b.y);
    t[2] = __float2bfloat16((xv.z - mean) * inv * g.z + b.z);
    t[3] = __float2bfloat16((xv.w - mean) * inv * g.w + b.w);
    *reinterpret_cast<ushort4*>(out + (size_t)row * Dm + tid * 4) =
        *reinterpret_cast<ushort4*>(t);
}

// ---------------- bf16 MFMA GEMM, 8-phase pipelined (m201-style) -----------
// C = A[M,K] x Bt[N,K]^T. BM=256, BK=64, 8 waves (2M x 4N). Per K-tile:
// 4 phases (mh,kk), each {8 ds_read ; 1 chunk prefetch ; barrier ; lgkmcnt(0);
// 16 MFMA ; counted vmcnt ; barrier}. Chunks [B0(,B1),A0,A1], dist-1 prefetch,
// vmcnt(4) @p1 (guarantees A1 cur), vmcnt(2) @p3 (guarantees B*,A0 next).
// EPI 0: bf16 C                EPI 1: f32 C = acc + bias + res
// EPI 2: bf16 C = gelu(acc+b)  EPI 3: f32 C += acc + bias
template<int BN_, int EPI>
__global__ void __launch_bounds__(512) gemm8p(const __hip_bfloat16* __restrict__ A, int lda,
                                              const __hip_bfloat16* __restrict__ Bt, int ldb,
                                              const float* __restrict__ bias,
                                              const float* __restrict__ res,
                                              void* __restrict__ Cout, int ldc,
                                              int nbx, int K) {
    constexpr int BCH = BN_ / 128;           // B chunks per K-tile (2 or 1)
    constexpr int CH  = 2 + BCH;             // total chunks per K-tile
    constexpr int NI  = BN_ / 64;            // per-wave N frags (4 or 2)
    constexpr int WNS = BN_ / 4;             // per-wave N span
    __shared__ __hip_bfloat16 As[2][256 * 64];
    __shared__ __hip_bfloat16 Bs[2][BN_ * 64];
    const int tid = threadIdx.x, l = tid & 63, w = tid >> 6;
    const int lr = l & 15, lg = l >> 4;
    const int nwg = gridDim.x;
    const int sbid = (blockIdx.x & 7) * (nwg >> 3) + (blockIdx.x >> 3);
    const int bx = sbid % nbx, by = sbid / nbx;
    const int m0 = by * 256, n0 = bx * BN_;
    const int wr = w >> 2, wc = w & 3;
    const int srow = l >> 3;                 // row within 8-row staging group
    const int scol = ((l & 7) ^ srow) * 8;   // pre-swizzled source col (elems)
    const int NK = K >> 6;

    auto stage_chunk = [&](int c, int t) {
        const int bsel = t & 1;
        const int k0 = t * 64;
        #pragma unroll
        for (int j = 0; j < 2; j++) {
            const int rb = j * 64 + w * 8;
            if (c < BCH) {
                gload16(Bt + (size_t)(n0 + c * 128 + rb + srow) * ldb + k0 + scol,
                        &Bs[bsel][(c * 128 + rb) * 64]);
            } else {
                const int ar = c - BCH;
                gload16(A + (size_t)(m0 + ar * 128 + rb + srow) * lda + k0 + scol,
                        &As[bsel][(ar * 128 + rb) * 64]);
            }
        }
    };

    f32x4 acc[2][4][NI] = {};

    // prologue: stage all chunks of tile 0; guarantee all but last; barrier
    #pragma unroll
    for (int c = 0; c < CH; c++) stage_chunk(c, 0);
    asm volatile("s_waitcnt vmcnt(2)" ::: "memory");
    __builtin_amdgcn_s_barrier();

#define PHASE(MH, KK, ISSUE_C, WAITV)                                              \
    {                                                                              \
        bfrag a_[4], b_[NI];                                                       \
        const char* Ab = (const char*)&As[cur][0];                                 \
        const char* Bb = (const char*)&Bs[cur][0];                                 \
        _Pragma("unroll")                                                          \
        for (int mi = 0; mi < 4; mi++) {                                           \
            const int row = (MH) * 128 + wr * 64 + mi * 16 + lr;                   \
            a_[mi] = *(const bfrag*)(Ab + row * 128 + ((((KK) * 4 + lg) ^ (row & 7)) << 4)); \
        }                                                                          \
        _Pragma("unroll")                                                          \
        for (int ni = 0; ni < NI; ni++) {                                          \
            const int row = wc * WNS + ni * 16 + lr;                               \
            b_[ni] = *(const bfrag*)(Bb + row * 128 + ((((KK) * 4 + lg) ^ (row & 7)) << 4)); \
        }                                                                          \
        if ((ISSUE_C) < CH && t + 1 < NK) stage_chunk((ISSUE_C), t + 1);           \
        __builtin_amdgcn_s_barrier();                                              \
        asm volatile("s_waitcnt lgkmcnt(0)" ::: "memory");                         \
        __builtin_amdgcn_sched_barrier(0);                                         \
        __builtin_amdgcn_s_setprio(1);                                             \
        _Pragma("unroll")                                                          \
        for (int mi = 0; mi < 4; mi++)                                             \
            _Pragma("unroll")                                                      \
            for (int ni = 0; ni < NI; ni++)                                        \
                acc[MH][mi][ni] = __builtin_amdgcn_mfma_f32_16x16x32_bf16(         \
                    a_[mi], b_[ni], acc[MH][mi][ni], 0, 0, 0);                     \
        __builtin_amdgcn_s_setprio(0);                                             \
        if ((WAITV) == 4) asm volatile("s_waitcnt vmcnt(4)" ::: "memory");         \
        if ((WAITV) == 2) asm volatile("s_waitcnt vmcnt(2)" ::: "memory");         \
        __builtin_amdgcn_s_barrier();                                              \
    }

    for (int t = 0; t < NK; t++) {
        const int cur = t & 1;
        PHASE(0, 0, 0, -1)
        PHASE(0, 1, 1, 4)
        PHASE(1, 0, 2, -1)
        PHASE(1, 1, 3, 2)
    }
#undef PHASE

    #pragma unroll
    for (int mh = 0; mh < 2; mh++) {
        #pragma unroll
        for (int mi = 0; mi < 4; mi++) {
            #pragma unroll
            for (int ni = 0; ni < NI; ni++) {
                #pragma unroll
                for (int rg = 0; rg < 4; rg++) {
                    const int row = m0 + mh * 128 + wr * 64 + mi * 16 + lg * 4 + rg;
                    const int col = n0 + wc * WNS + ni * 16 + lr;
                    const size_t off = (size_t)row * ldc + col;
                    const float v = acc[mh][mi][ni][rg];
                    if (EPI == 0) {
                        ((__hip_bfloat16*)Cout)[off] = __float2bfloat16(v);
                    } else if (EPI == 1) {
                        ((float*)Cout)[off] = v + bias[col] + res[off];
                    } else if (EPI == 2) {
                        ((__hip_bfloat16*)Cout)[off] = __float2bfloat16(gelu_f(v + bias[col]));
                    } else {
                        ((float*)Cout)[off] = ((float*)Cout)[off] + v + bias[col];
                    }
                }
            }
        }
    }
}

// ---------------- Flash attention, bf16 MFMA -------------------------------
// QKV [NT][3072]: Q at col 0, K at 1024, V at 2048 (+h*64). Block = (b,h,qt):
// 64 Q-rows, 4 waves x 16 rows. K/V tiles of 64 keys, online softmax.
__global__ void __launch_bounds__(256) attn_mfma(const __hip_bfloat16* __restrict__ QKV,
                                                 __hip_bfloat16* __restrict__ Oc) {
    constexpr int LDQ = 3072;
    __shared__ __hip_bfloat16 Qs[64 * 64];
    __shared__ __hip_bfloat16 Ks[64 * 64];
    __shared__ __hip_bfloat16 Vts[64 * 64];   // V^T [feat][key]
    __shared__ __hip_bfloat16 Ps[4][16 * 64]; // per-wave P
    const int tid = threadIdx.x, l = tid & 63, w = tid >> 6;
    const int lr = l & 15, lg = l >> 4;
    const int qt = blockIdx.x & 7;
    const int h  = (blockIdx.x >> 3) & 15;
    const int b  = blockIdx.x >> 7;

    const __hip_bfloat16* Qg = QKV + (size_t)(b * Ss + qt * 64) * LDQ + h * 64;
    const __hip_bfloat16* Kg = QKV + (size_t)(b * Ss) * LDQ + 1024 + h * 64;
    const __hip_bfloat16* Vg = QKV + (size_t)(b * Ss) * LDQ + 2048 + h * 64;

    const int r8 = l >> 3;                    // row-in-slot 0..7
    const int scol = 8 * ((l & 7) ^ r8);      // pre-swizzled source col (elems)

    #pragma unroll
    for (int j = 0; j < 2; j++) {
        const int slot = w * 2 + j;
        gload16(Qg + (size_t)(slot * 8 + r8) * LDQ + scol, Qs + slot * 512);
    }

    float m_run[4] = {-1e30f, -1e30f, -1e30f, -1e30f};
    float l_run[4] = {0.f, 0.f, 0.f, 0.f};
    f32x4 acc_o[4] = {};

    for (int kt = 0; kt <= qt; ++kt) {
        __syncthreads();   // prev-iter LDS reads done (iter 0: Q staged)
        #pragma unroll
        for (int j = 0; j < 2; j++) {
            const int slot = w * 2 + j;
            gload16(Kg + (size_t)(kt * 64 + slot * 8 + r8) * LDQ + scol, Ks + slot * 512);
        }
        // V^T: reg-stage with swizzled transpose writes
        unsigned short* vt = reinterpret_cast<unsigned short*>(Vts);
        #pragma unroll
        for (int j = 0; j < 2; j++) {
            const int e = tid + j * 256;
            const int key = e >> 3, f0 = (e & 7) * 8;
            const uint4 raw = *reinterpret_cast<const uint4*>(
                Vg + (size_t)(kt * 64 + key) * LDQ + f0);
            const unsigned int rw[4] = {raw.x, raw.y, raw.z, raw.w};
            #pragma unroll
            for (int e2 = 0; e2 < 8; e2++) {
                const int feat = f0 + e2;
                const int ad = feat * 128 + ((key * 2) ^ ((feat & 7) << 4));
                vt[ad >> 1] = (unsigned short)(rw[e2 >> 1] >> ((e2 & 1) * 16));
            }
        }
        __syncthreads();   // K, V^T staged

        // QK^T -> S [16 q-rows][64 keys] per wave
        f32x4 s4[4] = {};
        #pragma unroll
        for (int kk = 0; kk < 2; kk++) {
            const bfrag aq = *reinterpret_cast<const bfrag*>(
                (const char*)Qs + SWZ(w * 16 + lr, kk * 64 + lg * 16));
            #pragma unroll
            for (int ni = 0; ni < 4; ni++) {
                const bfrag bk = *reinterpret_cast<const bfrag*>(
                    (const char*)Ks + SWZ(ni * 16 + lr, kk * 64 + lg * 16));
                s4[ni] = __builtin_amdgcn_mfma_f32_16x16x32_bf16(aq, bk, s4[ni], 0, 0, 0);
            }
        }
        float p[4][4];
        #pragma unroll
        for (int ni = 0; ni < 4; ni++)
            #pragma unroll
            for (int rg = 0; rg < 4; rg++)
                p[ni][rg] = s4[ni][rg] * 0.125f;
        if (kt == qt) {   // causal mask on diagonal tile
            #pragma unroll
            for (int ni = 0; ni < 4; ni++)
                #pragma unroll
                for (int rg = 0; rg < 4; rg++)
                    if (ni * 16 + lr > w * 16 + lg * 4 + rg) p[ni][rg] = -1e30f;
        }
        float sf[4];
        #pragma unroll
        for (int rg = 0; rg < 4; rg++) {
            float mx = fmaxf(fmaxf(p[0][rg], p[1][rg]), fmaxf(p[2][rg], p[3][rg]));
            #pragma unroll
            for (int o = 1; o < 16; o <<= 1) mx = fmaxf(mx, __shfl_xor(mx, o, 64));
            const float mn = fmaxf(m_run[rg], mx);
            sf[rg] = __expf(m_run[rg] - mn);
            m_run[rg] = mn;
        }
        float rsum[4] = {};
        #pragma unroll
        for (int ni = 0; ni < 4; ni++)
            #pragma unroll
            for (int rg = 0; rg < 4; rg++) {
                const float e = __expf(p[ni][rg] - m_run[rg]);
                p[ni][rg] = e;
                rsum[rg] += e;
            }
        #pragma unroll
        for (int rg = 0; rg < 4; rg++) {
            #pragma unroll
            for (int o = 1; o < 16; o <<= 1) rsum[rg] += __shfl_xor(rsum[rg], o, 64);
            l_run[rg] = l_run[rg] * sf[rg] + rsum[rg];
        }
        #pragma unroll
        for (int di = 0; di < 4; di++)
            #pragma unroll
            for (int rg = 0; rg < 4; rg++)
                acc_o[di][rg] *= sf[rg];
        // P -> bf16 -> per-wave LDS (swizzled), then PV
        unsigned short* pw = reinterpret_cast<unsigned short*>(Ps[w]);
        #pragma unroll
        for (int ni = 0; ni < 4; ni++)
            #pragma unroll
            for (int rg = 0; rg < 4; rg++) {
                const int prow = lg * 4 + rg;
                const int ad = SWZ(prow, (ni * 16 + lr) * 2);
                __hip_bfloat16 pb = __float2bfloat16(p[ni][rg]);
                pw[ad >> 1] = *reinterpret_cast<unsigned short*>(&pb);
            }
        #pragma unroll
        for (int kk = 0; kk < 2; kk++) {
            const bfrag pa = *reinterpret_cast<const bfrag*>(
                (const char*)Ps[w] + SWZ(lr, kk * 64 + lg * 16));
            #pragma unroll
            for (int di = 0; di < 4; di++) {
                const bfrag vb = *reinterpret_cast<const bfrag*>(
                    (const char*)Vts + SWZ(di * 16 + lr, kk * 64 + lg * 16));
                acc_o[di] = __builtin_amdgcn_mfma_f32_16x16x32_bf16(pa, vb, acc_o[di], 0, 0, 0);
            }
        }
    }
    #pragma unroll
    for (int di = 0; di < 4; di++)
        #pragma unroll
        for (int rg = 0; rg < 4; rg++) {
            const int q = qt * 64 + w * 16 + lg * 4 + rg;
            const float v = acc_o[di][rg] / l_run[rg];
            Oc[(size_t)(b * Ss + q) * Dm + h * 64 + di * 16 + lr] = __float2bfloat16(v);
        }
}

extern "C" void kernel_launch(void* const* d_in, const int* in_sizes, int n_in,
                              void* d_out, int out_size, void* d_ws, size_t ws_size,
                              hipStream_t stream) {
    const float* x   = (const float*)d_in[0];
    const float* Wq  = (const float*)d_in[1];
    const float* Wk  = (const float*)d_in[2];
    const float* Wv  = (const float*)d_in[3];
    const float* Wo  = (const float*)d_in[4];
    const float* bo  = (const float*)d_in[5];
    const float* g1  = (const float*)d_in[6];
    const float* be1 = (const float*)d_in[7];
    const float* g2  = (const float*)d_in[8];
    const float* be2 = (const float*)d_in[9];
    const float* W1  = (const float*)d_in[10];
    const float* b1  = (const float*)d_in[11];
    const float* W2  = (const float*)d_in[12];
    const float* b2  = (const float*)d_in[13];
    float* out = (float*)d_out;

    // workspace (bytes): bf16 weights 24MB | n1/concat/n2 16MB | QKV 48MB, h1 64MB
    char* wsb = (char*)d_ws;
    __hip_bfloat16* WqkvT = (__hip_bfloat16*)(wsb);                 // [3072][1024]
    __hip_bfloat16* WoT   = (__hip_bfloat16*)(wsb + 6291456);       // [1024][1024]
    __hip_bfloat16* W1T   = (__hip_bfloat16*)(wsb + 8388608);       // [4096][1024]
    __hip_bfloat16* W2T   = (__hip_bfloat16*)(wsb + 16777216);      // [1024][4096]
    __hip_bfloat16* n1    = (__hip_bfloat16*)(wsb + 25165824);      // [8192][1024]
    __hip_bfloat16* QKV   = (__hip_bfloat16*)(wsb + 41943040);      // [8192][3072]
    __hip_bfloat16* concat = n1;                                    // alias (n1 dead)
    __hip_bfloat16* n2     = n1;                                    // alias (concat dead)
    __hip_bfloat16* h1     = QKV;                                   // alias (QKV dead), [8192][4096]

    // weight transpose+convert
    transpose_cvt<<<dim3(2, 32, 16), 256, 0, stream>>>(Wq, WqkvT,              1024, 64, 65536, 65536);
    transpose_cvt<<<dim3(2, 32, 16), 256, 0, stream>>>(Wk, WqkvT + 1024 * 1024, 1024, 64, 65536, 65536);
    transpose_cvt<<<dim3(2, 32, 16), 256, 0, stream>>>(Wv, WqkvT + 2048 * 1024, 1024, 64, 65536, 65536);
    transpose_cvt<<<dim3(32, 32, 1), 256, 0, stream>>>(Wo, WoT, 1024, 1024, 0, 0);
    transpose_cvt<<<dim3(128, 32, 1), 256, 0, stream>>>(W1, W1T, 1024, 4096, 0, 0);
    transpose_cvt<<<dim3(32, 128, 1), 256, 0, stream>>>(W2, W2T, 4096, 1024, 0, 0);

    ln_bf16<<<NT, 256, 0, stream>>>(x, g1, be1, n1);
    // QKV: M=8192 N=3072 K=1024, 256x256 tiles -> 12x32=384 blocks
    gemm8p<256, 0><<<384, 512, 0, stream>>>(n1, Dm, WqkvT, Dm, nullptr, nullptr,
                                            QKV, 3072, 12, Dm);
    attn_mfma<<<NT * Hh / 64, 256, 0, stream>>>(QKV, concat);
    // proj: N=1024, 256x128 tiles -> 8x32=256 blocks
    gemm8p<128, 1><<<256, 512, 0, stream>>>(concat, Dm, WoT, Dm, bo, x,
                                            out, Dm, 8, Dm);
    ln_bf16<<<NT, 256, 0, stream>>>(out, g2, be2, n2);
    // FFN1: N=4096, 256x256 tiles -> 16x32=512 blocks
    gemm8p<256, 2><<<512, 512, 0, stream>>>(n2, Dm, W1T, Dm, b1, nullptr,
                                            h1, Ff, 16, Dm);
    // FFN2: M=8192 N=1024 K=4096, 256x128 tiles -> 256 blocks
    gemm8p<128, 3><<<256, 512, 0, stream>>>(h1, Ff, W2T, Ff, b2, nullptr,
                                            out, Dm, 8, Ff);
}

// Round 5
// 425.836 us; speedup vs baseline: 1.1820x; 1.1284x over previous
//
#include <hip/hip_runtime.h>
#include <hip/hip_bf16.h>
#include <math.h>

constexpr int Dm = 1024;
constexpr int Hh = 16;
constexpr int Ff = 4096;
constexpr int Ss = 512;
constexpr int Bbatch = 16;
constexpr int NT = Bbatch * Ss;   // 8192 tokens
constexpr float EPSc = 1e-5f;

typedef __attribute__((ext_vector_type(8))) short bfrag;   // 8 bf16 (4 VGPR)
typedef __attribute__((ext_vector_type(4))) float f32x4;

// tanh-form GELU, one v_exp, NaN-safe at +-inf of e (1 - 2/(e+1))
static __device__ __forceinline__ float gelu_f(float v) {
    const float u = v * (0.7978845608f + 0.0356774081f * v * v);
    const float e = __expf(2.0f * u);
    const float th = 1.0f - 2.0f / (e + 1.0f);
    return 0.5f * v * (1.0f + th);
}

static __device__ __forceinline__ void gload16(const void* g, void* l) {
    __builtin_amdgcn_global_load_lds((__attribute__((address_space(1))) void*)g,
                                     (__attribute__((address_space(3))) void*)l,
                                     16, 0, 0);
}

// XOR swizzle for [rows][128B-row] LDS tiles (G4): byte ^= ((row&7)<<4)
#define SWZ(row, colb) ((row) * 128 + ((colb) ^ (((row) & 7) << 4)))

// ---------------- transpose + fp32->bf16 convert: in [R][C] -> out [C][R] ---
__global__ void __launch_bounds__(256) transpose_cvt(const float* __restrict__ in,
                                                     __hip_bfloat16* __restrict__ out,
                                                     int R, int C,
                                                     long in_zs, long out_zs) {
    __shared__ float tile[32][33];
    const float* inz = in + (size_t)blockIdx.z * in_zs;
    __hip_bfloat16* outz = out + (size_t)blockIdx.z * out_zs;
    const int c0 = blockIdx.x * 32, r0 = blockIdx.y * 32;
    const int tx = threadIdx.x & 31, ty4 = (threadIdx.x >> 5) * 4;
    #pragma unroll
    for (int i = 0; i < 4; i++)
        tile[ty4 + i][tx] = inz[(size_t)(r0 + ty4 + i) * C + c0 + tx];
    __syncthreads();
    #pragma unroll
    for (int i = 0; i < 4; i++)
        outz[(size_t)(c0 + ty4 + i) * R + r0 + tx] = __float2bfloat16(tile[tx][ty4 + i]);
}

// ---------------- LayerNorm fp32 in -> bf16 out ----------------------------
__global__ void __launch_bounds__(256) ln_bf16(const float* __restrict__ x,
                                               const float* __restrict__ gamma,
                                               const float* __restrict__ beta,
                                               __hip_bfloat16* __restrict__ out) {
    const int row = blockIdx.x;
    const int tid = threadIdx.x;
    const int lane = tid & 63, w = tid >> 6;
    float4 xv = reinterpret_cast<const float4*>(x + (size_t)row * Dm)[tid];
    float s  = xv.x + xv.y + xv.z + xv.w;
    float ss = xv.x * xv.x + xv.y * xv.y + xv.z * xv.z + xv.w * xv.w;
    #pragma unroll
    for (int o = 32; o > 0; o >>= 1) {
        s  += __shfl_down(s,  o, 64);
        ss += __shfl_down(ss, o, 64);
    }
    __shared__ float red[2][4];
    if (lane == 0) { red[0][w] = s; red[1][w] = ss; }
    __syncthreads();
    float st  = red[0][0] + red[0][1] + red[0][2] + red[0][3];
    float sst = red[1][0] + red[1][1] + red[1][2] + red[1][3];
    float mean = st * (1.0f / Dm);
    float var  = sst * (1.0f / Dm) - mean * mean;
    float inv  = rsqrtf(var + EPSc);
    float4 g = reinterpret_cast<const float4*>(gamma)[tid];
    float4 b = reinterpret_cast<const float4*>(beta)[tid];
    __hip_bfloat16 t[4] __attribute__((aligned(8)));
    t[0] = __float2bfloat16((xv.x - mean) * inv * g.x + b.x);
    t[1] = __float2bfloat16((xv.y - mean) * inv * g.y + b.y);
    t[2] = __float2bfloat16((xv.z - mean) * inv * g.z + b.z);
    t[3] = __float2bfloat16((xv.w - mean) * inv * g.w + b.w);
    *reinterpret_cast<ushort4*>(out + (size_t)row * Dm + tid * 4) =
        *reinterpret_cast<ushort4*>(t);
}

// ---------------- bf16 MFMA GEMM (m97 structure + swizzle): ----------------
// C = A[M,K] x Bt[N,K]^T. 128x128 tile, BK=64, 256 thr (4 waves 2x2),
// single-buffer LDS, global_load_lds staging with pre-swizzled source,
// swizzled ds_read_b128 (conflict-free), plain __syncthreads 2-barrier loop.
// Occupancy-driven overlap (~3 blocks/CU) per m97/m114.
// EPI 0: bf16 C                EPI 1: f32 C = acc + bias + res
// EPI 2: bf16 C = gelu(acc+b)  EPI 3: f32 C += acc + bias
template<int EPI>
__global__ void __launch_bounds__(256) gemm_m97(const __hip_bfloat16* __restrict__ A, int lda,
                                                const __hip_bfloat16* __restrict__ Bt, int ldb,
                                                const float* __restrict__ bias,
                                                const float* __restrict__ res,
                                                void* __restrict__ Cout, int ldc,
                                                int nbx, int K) {
    __shared__ __hip_bfloat16 As[128 * 64];   // [row][64 k] 128B rows, swizzled
    __shared__ __hip_bfloat16 Bs[128 * 64];
    const int tid = threadIdx.x, l = tid & 63, w = tid >> 6;
    const int lr = l & 15, lg = l >> 4;       // frag row-in-16, k-granule
    const int nwg = gridDim.x;
    const int sbid = (blockIdx.x & 7) * (nwg >> 3) + (blockIdx.x >> 3);
    const int bx = sbid % nbx, by = sbid / nbx;
    const int m0 = by * 128, n0 = bx * 128;
    const int wr = w >> 1, wc = w & 1;        // wave 2x2 -> 64x64 per wave
    const int srow = l >> 3;                  // staging row within 8-row group
    const int scol = ((l & 7) ^ srow) * 8;    // pre-swizzled source col (elems)

    f32x4 acc[4][4] = {};
    for (int k0 = 0; k0 < K; k0 += 64) {
        // stage A,B tiles: 4 waves x 4 calls each of 8 rows x 128B, linear dest
        #pragma unroll
        for (int j = 0; j < 4; j++) {
            const int rb = w * 32 + j * 8;
            gload16(A  + (size_t)(m0 + rb + srow) * lda + k0 + scol, As + rb * 64);
            gload16(Bt + (size_t)(n0 + rb + srow) * ldb + k0 + scol, Bs + rb * 64);
        }
        __syncthreads();
        #pragma unroll
        for (int kk = 0; kk < 2; kk++) {
            bfrag a[4], b[4];
            #pragma unroll
            for (int mi = 0; mi < 4; mi++) {
                const int row = wr * 64 + mi * 16 + lr;
                a[mi] = *(const bfrag*)((const char*)As + SWZ(row, (kk * 4 + lg) * 16));
            }
            #pragma unroll
            for (int ni = 0; ni < 4; ni++) {
                const int row = wc * 64 + ni * 16 + lr;
                b[ni] = *(const bfrag*)((const char*)Bs + SWZ(row, (kk * 4 + lg) * 16));
            }
            #pragma unroll
            for (int mi = 0; mi < 4; mi++)
                #pragma unroll
                for (int ni = 0; ni < 4; ni++)
                    acc[mi][ni] = __builtin_amdgcn_mfma_f32_16x16x32_bf16(a[mi], b[ni], acc[mi][ni], 0, 0, 0);
        }
        __syncthreads();
    }
    const int rb = m0 + wr * 64 + lg * 4;
    const int cb = n0 + wc * 64 + lr;
    #pragma unroll
    for (int mi = 0; mi < 4; mi++) {
        #pragma unroll
        for (int ni = 0; ni < 4; ni++) {
            #pragma unroll
            for (int rg = 0; rg < 4; rg++) {
                const int row = rb + mi * 16 + rg;
                const int col = cb + ni * 16;
                const size_t off = (size_t)row * ldc + col;
                const float v = acc[mi][ni][rg];
                if (EPI == 0) {
                    ((__hip_bfloat16*)Cout)[off] = __float2bfloat16(v);
                } else if (EPI == 1) {
                    ((float*)Cout)[off] = v + bias[col] + res[off];
                } else if (EPI == 2) {
                    ((__hip_bfloat16*)Cout)[off] = __float2bfloat16(gelu_f(v + bias[col]));
                } else {
                    ((float*)Cout)[off] = ((float*)Cout)[off] + v + bias[col];
                }
            }
        }
    }
}

// ---------------- Flash attention, bf16 MFMA -------------------------------
// QKV [NT][3072]: Q at col 0, K at 1024, V at 2048 (+h*64). Block = (b,h,qt):
// 64 Q-rows, 4 waves x 16 rows. K/V tiles of 64 keys, online softmax.
__global__ void __launch_bounds__(256) attn_mfma(const __hip_bfloat16* __restrict__ QKV,
                                                 __hip_bfloat16* __restrict__ Oc) {
    constexpr int LDQ = 3072;
    __shared__ __hip_bfloat16 Qs[64 * 64];
    __shared__ __hip_bfloat16 Ks[64 * 64];
    __shared__ __hip_bfloat16 Vts[64 * 64];   // V^T [feat][key]
    __shared__ __hip_bfloat16 Ps[4][16 * 64]; // per-wave P
    const int tid = threadIdx.x, l = tid & 63, w = tid >> 6;
    const int lr = l & 15, lg = l >> 4;
    const int qt = blockIdx.x & 7;
    const int h  = (blockIdx.x >> 3) & 15;
    const int b  = blockIdx.x >> 7;

    const __hip_bfloat16* Qg = QKV + (size_t)(b * Ss + qt * 64) * LDQ + h * 64;
    const __hip_bfloat16* Kg = QKV + (size_t)(b * Ss) * LDQ + 1024 + h * 64;
    const __hip_bfloat16* Vg = QKV + (size_t)(b * Ss) * LDQ + 2048 + h * 64;

    const int r8 = l >> 3;                    // row-in-slot 0..7
    const int scol = 8 * ((l & 7) ^ r8);      // pre-swizzled source col (elems)

    #pragma unroll
    for (int j = 0; j < 2; j++) {
        const int slot = w * 2 + j;
        gload16(Qg + (size_t)(slot * 8 + r8) * LDQ + scol, Qs + slot * 512);
    }

    float m_run[4] = {-1e30f, -1e30f, -1e30f, -1e30f};
    float l_run[4] = {0.f, 0.f, 0.f, 0.f};
    f32x4 acc_o[4] = {};

    for (int kt = 0; kt <= qt; ++kt) {
        __syncthreads();   // prev-iter LDS reads done (iter 0: Q staged)
        #pragma unroll
        for (int j = 0; j < 2; j++) {
            const int slot = w * 2 + j;
            gload16(Kg + (size_t)(kt * 64 + slot * 8 + r8) * LDQ + scol, Ks + slot * 512);
        }
        // V^T: reg-stage with swizzled transpose writes
        unsigned short* vt = reinterpret_cast<unsigned short*>(Vts);
        #pragma unroll
        for (int j = 0; j < 2; j++) {
            const int e = tid + j * 256;
            const int key = e >> 3, f0 = (e & 7) * 8;
            const uint4 raw = *reinterpret_cast<const uint4*>(
                Vg + (size_t)(kt * 64 + key) * LDQ + f0);
            const unsigned int rw[4] = {raw.x, raw.y, raw.z, raw.w};
            #pragma unroll
            for (int e2 = 0; e2 < 8; e2++) {
                const int feat = f0 + e2;
                const int ad = feat * 128 + ((key * 2) ^ ((feat & 7) << 4));
                vt[ad >> 1] = (unsigned short)(rw[e2 >> 1] >> ((e2 & 1) * 16));
            }
        }
        __syncthreads();   // K, V^T staged

        // QK^T -> S [16 q-rows][64 keys] per wave
        f32x4 s4[4] = {};
        #pragma unroll
        for (int kk = 0; kk < 2; kk++) {
            const bfrag aq = *reinterpret_cast<const bfrag*>(
                (const char*)Qs + SWZ(w * 16 + lr, kk * 64 + lg * 16));
            #pragma unroll
            for (int ni = 0; ni < 4; ni++) {
                const bfrag bk = *reinterpret_cast<const bfrag*>(
                    (const char*)Ks + SWZ(ni * 16 + lr, kk * 64 + lg * 16));
                s4[ni] = __builtin_amdgcn_mfma_f32_16x16x32_bf16(aq, bk, s4[ni], 0, 0, 0);
            }
        }
        float p[4][4];
        #pragma unroll
        for (int ni = 0; ni < 4; ni++)
            #pragma unroll
            for (int rg = 0; rg < 4; rg++)
                p[ni][rg] = s4[ni][rg] * 0.125f;
        if (kt == qt) {   // causal mask on diagonal tile
            #pragma unroll
            for (int ni = 0; ni < 4; ni++)
                #pragma unroll
                for (int rg = 0; rg < 4; rg++)
                    if (ni * 16 + lr > w * 16 + lg * 4 + rg) p[ni][rg] = -1e30f;
        }
        float sf[4];
        #pragma unroll
        for (int rg = 0; rg < 4; rg++) {
            float mx = fmaxf(fmaxf(p[0][rg], p[1][rg]), fmaxf(p[2][rg], p[3][rg]));
            #pragma unroll
            for (int o = 1; o < 16; o <<= 1) mx = fmaxf(mx, __shfl_xor(mx, o, 64));
            const float mn = fmaxf(m_run[rg], mx);
            sf[rg] = __expf(m_run[rg] - mn);
            m_run[rg] = mn;
        }
        float rsum[4] = {};
        #pragma unroll
        for (int ni = 0; ni < 4; ni++)
            #pragma unroll
            for (int rg = 0; rg < 4; rg++) {
                const float e = __expf(p[ni][rg] - m_run[rg]);
                p[ni][rg] = e;
                rsum[rg] += e;
            }
        #pragma unroll
        for (int rg = 0; rg < 4; rg++) {
            #pragma unroll
            for (int o = 1; o < 16; o <<= 1) rsum[rg] += __shfl_xor(rsum[rg], o, 64);
            l_run[rg] = l_run[rg] * sf[rg] + rsum[rg];
        }
        #pragma unroll
        for (int di = 0; di < 4; di++)
            #pragma unroll
            for (int rg = 0; rg < 4; rg++)
                acc_o[di][rg] *= sf[rg];
        // P -> bf16 -> per-wave LDS (swizzled), then PV
        unsigned short* pw = reinterpret_cast<unsigned short*>(Ps[w]);
        #pragma unroll
        for (int ni = 0; ni < 4; ni++)
            #pragma unroll
            for (int rg = 0; rg < 4; rg++) {
                const int prow = lg * 4 + rg;
                const int ad = SWZ(prow, (ni * 16 + lr) * 2);
                __hip_bfloat16 pb = __float2bfloat16(p[ni][rg]);
                pw[ad >> 1] = *reinterpret_cast<unsigned short*>(&pb);
            }
        #pragma unroll
        for (int kk = 0; kk < 2; kk++) {
            const bfrag pa = *reinterpret_cast<const bfrag*>(
                (const char*)Ps[w] + SWZ(lr, kk * 64 + lg * 16));
            #pragma unroll
            for (int di = 0; di < 4; di++) {
                const bfrag vb = *reinterpret_cast<const bfrag*>(
                    (const char*)Vts + SWZ(di * 16 + lr, kk * 64 + lg * 16));
                acc_o[di] = __builtin_amdgcn_mfma_f32_16x16x32_bf16(pa, vb, acc_o[di], 0, 0, 0);
            }
        }
    }
    #pragma unroll
    for (int di = 0; di < 4; di++)
        #pragma unroll
        for (int rg = 0; rg < 4; rg++) {
            const int q = qt * 64 + w * 16 + lg * 4 + rg;
            const float v = acc_o[di][rg] / l_run[rg];
            Oc[(size_t)(b * Ss + q) * Dm + h * 64 + di * 16 + lr] = __float2bfloat16(v);
        }
}

extern "C" void kernel_launch(void* const* d_in, const int* in_sizes, int n_in,
                              void* d_out, int out_size, void* d_ws, size_t ws_size,
                              hipStream_t stream) {
    const float* x   = (const float*)d_in[0];
    const float* Wq  = (const float*)d_in[1];
    const float* Wk  = (const float*)d_in[2];
    const float* Wv  = (const float*)d_in[3];
    const float* Wo  = (const float*)d_in[4];
    const float* bo  = (const float*)d_in[5];
    const float* g1  = (const float*)d_in[6];
    const float* be1 = (const float*)d_in[7];
    const float* g2  = (const float*)d_in[8];
    const float* be2 = (const float*)d_in[9];
    const float* W1  = (const float*)d_in[10];
    const float* b1  = (const float*)d_in[11];
    const float* W2  = (const float*)d_in[12];
    const float* b2  = (const float*)d_in[13];
    float* out = (float*)d_out;

    // workspace (bytes): bf16 weights 24MB | n1/concat/n2 16MB | QKV 48MB, h1 64MB
    char* wsb = (char*)d_ws;
    __hip_bfloat16* WqkvT = (__hip_bfloat16*)(wsb);                 // [3072][1024]
    __hip_bfloat16* WoT   = (__hip_bfloat16*)(wsb + 6291456);       // [1024][1024]
    __hip_bfloat16* W1T   = (__hip_bfloat16*)(wsb + 8388608);       // [4096][1024]
    __hip_bfloat16* W2T   = (__hip_bfloat16*)(wsb + 16777216);      // [1024][4096]
    __hip_bfloat16* n1    = (__hip_bfloat16*)(wsb + 25165824);      // [8192][1024]
    __hip_bfloat16* QKV   = (__hip_bfloat16*)(wsb + 41943040);      // [8192][3072]
    __hip_bfloat16* concat = n1;                                    // alias (n1 dead)
    __hip_bfloat16* n2     = n1;                                    // alias (concat dead)
    __hip_bfloat16* h1     = QKV;                                   // alias (QKV dead), [8192][4096]

    // weight transpose+convert
    transpose_cvt<<<dim3(2, 32, 16), 256, 0, stream>>>(Wq, WqkvT,              1024, 64, 65536, 65536);
    transpose_cvt<<<dim3(2, 32, 16), 256, 0, stream>>>(Wk, WqkvT + 1024 * 1024, 1024, 64, 65536, 65536);
    transpose_cvt<<<dim3(2, 32, 16), 256, 0, stream>>>(Wv, WqkvT + 2048 * 1024, 1024, 64, 65536, 65536);
    transpose_cvt<<<dim3(32, 32, 1), 256, 0, stream>>>(Wo, WoT, 1024, 1024, 0, 0);
    transpose_cvt<<<dim3(128, 32, 1), 256, 0, stream>>>(W1, W1T, 1024, 4096, 0, 0);
    transpose_cvt<<<dim3(32, 128, 1), 256, 0, stream>>>(W2, W2T, 4096, 1024, 0, 0);

    ln_bf16<<<NT, 256, 0, stream>>>(x, g1, be1, n1);
    // QKV: M=8192 N=3072 K=1024 -> 64x24 = 1536 blocks
    gemm_m97<0><<<1536, 256, 0, stream>>>(n1, Dm, WqkvT, Dm, nullptr, nullptr,
                                          QKV, 3072, 24, Dm);
    attn_mfma<<<NT * Hh / 64, 256, 0, stream>>>(QKV, concat);
    // proj: N=1024 -> 64x8 = 512 blocks
    gemm_m97<1><<<512, 256, 0, stream>>>(concat, Dm, WoT, Dm, bo, x,
                                         out, Dm, 8, Dm);
    ln_bf16<<<NT, 256, 0, stream>>>(out, g2, be2, n2);
    // FFN1: N=4096 -> 64x32 = 2048 blocks
    gemm_m97<2><<<2048, 256, 0, stream>>>(n2, Dm, W1T, Dm, b1, nullptr,
                                          h1, Ff, 32, Dm);
    // FFN2: M=8192 N=1024 K=4096 -> 512 blocks
    gemm_m97<3><<<512, 256, 0, stream>>>(h1, Ff, W2T, Ff, b2, nullptr,
                                         out, Dm, 8, Ff);
}

// Round 6
// 402.646 us; speedup vs baseline: 1.2501x; 1.0576x over previous
//
#include <hip/hip_runtime.h>
#include <hip/hip_bf16.h>
#include <math.h>

constexpr int Dm = 1024;
constexpr int Hh = 16;
constexpr int Ff = 4096;
constexpr int Ss = 512;
constexpr int Bbatch = 16;
constexpr int NT = Bbatch * Ss;   // 8192 tokens
constexpr float EPSc = 1e-5f;

typedef __attribute__((ext_vector_type(8))) short bfrag;   // 8 bf16 (4 VGPR)
typedef __attribute__((ext_vector_type(4))) float f32x4;

// tanh-form GELU, one v_exp, NaN-safe at +-inf of e (1 - 2/(e+1))
static __device__ __forceinline__ float gelu_f(float v) {
    const float u = v * (0.7978845608f + 0.0356774081f * v * v);
    const float e = __expf(2.0f * u);
    const float th = 1.0f - 2.0f / (e + 1.0f);
    return 0.5f * v * (1.0f + th);
}

static __device__ __forceinline__ void gload16(const void* g, void* l) {
    __builtin_amdgcn_global_load_lds((__attribute__((address_space(1))) void*)g,
                                     (__attribute__((address_space(3))) void*)l,
                                     16, 0, 0);
}

// XOR swizzle for [rows][128B-row] LDS tiles (G4): byte ^= ((row&7)<<4)
#define SWZ(row, colb) ((row) * 128 + ((colb) ^ (((row) & 7) << 4)))

// ---------------- transpose + fp32->bf16 convert: in [R][C] -> out [C][R] ---
__global__ void __launch_bounds__(256) transpose_cvt(const float* __restrict__ in,
                                                     __hip_bfloat16* __restrict__ out,
                                                     int R, int C,
                                                     long in_zs, long out_zs) {
    __shared__ float tile[32][33];
    const float* inz = in + (size_t)blockIdx.z * in_zs;
    __hip_bfloat16* outz = out + (size_t)blockIdx.z * out_zs;
    const int c0 = blockIdx.x * 32, r0 = blockIdx.y * 32;
    const int tx = threadIdx.x & 31, ty4 = (threadIdx.x >> 5) * 4;
    #pragma unroll
    for (int i = 0; i < 4; i++)
        tile[ty4 + i][tx] = inz[(size_t)(r0 + ty4 + i) * C + c0 + tx];
    __syncthreads();
    #pragma unroll
    for (int i = 0; i < 4; i++)
        outz[(size_t)(c0 + ty4 + i) * R + r0 + tx] = __float2bfloat16(tile[tx][ty4 + i]);
}

// ---------------- LayerNorm fp32 in -> bf16 out ----------------------------
__global__ void __launch_bounds__(256) ln_bf16(const float* __restrict__ x,
                                               const float* __restrict__ gamma,
                                               const float* __restrict__ beta,
                                               __hip_bfloat16* __restrict__ out) {
    const int row = blockIdx.x;
    const int tid = threadIdx.x;
    const int lane = tid & 63, w = tid >> 6;
    float4 xv = reinterpret_cast<const float4*>(x + (size_t)row * Dm)[tid];
    float s  = xv.x + xv.y + xv.z + xv.w;
    float ss = xv.x * xv.x + xv.y * xv.y + xv.z * xv.z + xv.w * xv.w;
    #pragma unroll
    for (int o = 32; o > 0; o >>= 1) {
        s  += __shfl_down(s,  o, 64);
        ss += __shfl_down(ss, o, 64);
    }
    __shared__ float red[2][4];
    if (lane == 0) { red[0][w] = s; red[1][w] = ss; }
    __syncthreads();
    float st  = red[0][0] + red[0][1] + red[0][2] + red[0][3];
    float sst = red[1][0] + red[1][1] + red[1][2] + red[1][3];
    float mean = st * (1.0f / Dm);
    float var  = sst * (1.0f / Dm) - mean * mean;
    float inv  = rsqrtf(var + EPSc);
    float4 g = reinterpret_cast<const float4*>(gamma)[tid];
    float4 b = reinterpret_cast<const float4*>(beta)[tid];
    __hip_bfloat16 t[4] __attribute__((aligned(8)));
    t[0] = __float2bfloat16((xv.x - mean) * inv * g.x + b.x);
    t[1] = __float2bfloat16((xv.y - mean) * inv * g.y + b.y);
    t[2] = __float2bfloat16((xv.z - mean) * inv * g.z + b.z);
    t[3] = __float2bfloat16((xv.w - mean) * inv * g.w + b.w);
    *reinterpret_cast<ushort4*>(out + (size_t)row * Dm + tid * 4) =
        *reinterpret_cast<ushort4*>(t);
}

// ---------------- bf16 MFMA GEMM: m97 structure + dbuf + counted vmcnt -----
// C = A[M,K] x Bt[N,K]^T. 128x128 tile, BK=64, 4 waves (2x2), 64 KiB LDS
// double-buffer. Per tile: issue STAGE(t+1) -> s_waitcnt vmcnt(8) (counted,
// never 0 mid-loop; guarantees tile-t data, keeps t+1 loads in flight) ->
// barrier -> swizzled ds_read + MFMA (setprio) -> barrier (WAR protect).
// EPI 0: bf16 C                EPI 1: f32 C = acc + bias + res
// EPI 2: bf16 C = gelu(acc+b)  EPI 3: f32 C += acc + bias
template<int EPI>
__global__ void __launch_bounds__(256) gemm_db(const __hip_bfloat16* __restrict__ A, int lda,
                                               const __hip_bfloat16* __restrict__ Bt, int ldb,
                                               const float* __restrict__ bias,
                                               const float* __restrict__ res,
                                               void* __restrict__ Cout, int ldc,
                                               int nbx, int K) {
    __shared__ __hip_bfloat16 As[2][128 * 64];   // [row][64 k] 128B rows, swizzled
    __shared__ __hip_bfloat16 Bs[2][128 * 64];
    const int tid = threadIdx.x, l = tid & 63, w = tid >> 6;
    const int lr = l & 15, lg = l >> 4;       // frag row-in-16, k-granule
    const int nwg = gridDim.x;
    const int sbid = (blockIdx.x & 7) * (nwg >> 3) + (blockIdx.x >> 3);
    const int bx = sbid % nbx, by = sbid / nbx;
    const int m0 = by * 128, n0 = bx * 128;
    const int wr = w >> 1, wc = w & 1;        // wave 2x2 -> 64x64 per wave
    const int srow = l >> 3;                  // staging row within 8-row group
    const int scol = ((l & 7) ^ srow) * 8;    // pre-swizzled source col (elems)
    const int NK = K >> 6;

    auto STAGE = [&](int t, int bsel) {       // 8 gload16 per wave
        const int k0 = t * 64;
        #pragma unroll
        for (int j = 0; j < 4; j++) {
            const int rb = w * 32 + j * 8;
            gload16(A  + (size_t)(m0 + rb + srow) * lda + k0 + scol, &As[bsel][rb * 64]);
            gload16(Bt + (size_t)(n0 + rb + srow) * ldb + k0 + scol, &Bs[bsel][rb * 64]);
        }
    };

    f32x4 acc[4][4] = {};
    STAGE(0, 0);
    for (int t = 0; t < NK; t++) {
        const int cur = t & 1;
        if (t + 1 < NK) {
            STAGE(t + 1, cur ^ 1);
            asm volatile("s_waitcnt vmcnt(8)" ::: "memory");   // tile-t ready; t+1 in flight
        } else {
            asm volatile("s_waitcnt vmcnt(0)" ::: "memory");
        }
        __builtin_amdgcn_s_barrier();
        __builtin_amdgcn_sched_barrier(0);
        const char* Ab = (const char*)&As[cur][0];
        const char* Bb = (const char*)&Bs[cur][0];
        #pragma unroll
        for (int kk = 0; kk < 2; kk++) {
            bfrag a[4], b[4];
            #pragma unroll
            for (int mi = 0; mi < 4; mi++) {
                const int row = wr * 64 + mi * 16 + lr;
                a[mi] = *(const bfrag*)(Ab + SWZ(row, (kk * 4 + lg) * 16));
            }
            #pragma unroll
            for (int ni = 0; ni < 4; ni++) {
                const int row = wc * 64 + ni * 16 + lr;
                b[ni] = *(const bfrag*)(Bb + SWZ(row, (kk * 4 + lg) * 16));
            }
            __builtin_amdgcn_s_setprio(1);
            #pragma unroll
            for (int mi = 0; mi < 4; mi++)
                #pragma unroll
                for (int ni = 0; ni < 4; ni++)
                    acc[mi][ni] = __builtin_amdgcn_mfma_f32_16x16x32_bf16(a[mi], b[ni], acc[mi][ni], 0, 0, 0);
            __builtin_amdgcn_s_setprio(0);
        }
        __builtin_amdgcn_sched_barrier(0);
        __builtin_amdgcn_s_barrier();         // all reads of buf[cur] done -> next STAGE may overwrite
    }
    const int rb = m0 + wr * 64 + lg * 4;
    const int cb = n0 + wc * 64 + lr;
    #pragma unroll
    for (int mi = 0; mi < 4; mi++) {
        #pragma unroll
        for (int ni = 0; ni < 4; ni++) {
            #pragma unroll
            for (int rg = 0; rg < 4; rg++) {
                const int row = rb + mi * 16 + rg;
                const int col = cb + ni * 16;
                const size_t off = (size_t)row * ldc + col;
                const float v = acc[mi][ni][rg];
                if (EPI == 0) {
                    ((__hip_bfloat16*)Cout)[off] = __float2bfloat16(v);
                } else if (EPI == 1) {
                    ((float*)Cout)[off] = v + bias[col] + res[off];
                } else if (EPI == 2) {
                    ((__hip_bfloat16*)Cout)[off] = __float2bfloat16(gelu_f(v + bias[col]));
                } else {
                    ((float*)Cout)[off] = ((float*)Cout)[off] + v + bias[col];
                }
            }
        }
    }
}

// ---------------- Flash attention, bf16 MFMA -------------------------------
// QKV [NT][3072]: Q at col 0, K at 1024, V at 2048 (+h*64). Block = (b,h,qt):
// 64 Q-rows, 4 waves x 16 rows. K/V tiles of 64 keys, online softmax.
__global__ void __launch_bounds__(256) attn_mfma(const __hip_bfloat16* __restrict__ QKV,
                                                 __hip_bfloat16* __restrict__ Oc) {
    constexpr int LDQ = 3072;
    __shared__ __hip_bfloat16 Qs[64 * 64];
    __shared__ __hip_bfloat16 Ks[64 * 64];
    __shared__ __hip_bfloat16 Vts[64 * 64];   // V^T [feat][key]
    __shared__ __hip_bfloat16 Ps[4][16 * 64]; // per-wave P
    const int tid = threadIdx.x, l = tid & 63, w = tid >> 6;
    const int lr = l & 15, lg = l >> 4;
    const int qt = blockIdx.x & 7;
    const int h  = (blockIdx.x >> 3) & 15;
    const int b  = blockIdx.x >> 7;

    const __hip_bfloat16* Qg = QKV + (size_t)(b * Ss + qt * 64) * LDQ + h * 64;
    const __hip_bfloat16* Kg = QKV + (size_t)(b * Ss) * LDQ + 1024 + h * 64;
    const __hip_bfloat16* Vg = QKV + (size_t)(b * Ss) * LDQ + 2048 + h * 64;

    const int r8 = l >> 3;                    // row-in-slot 0..7
    const int scol = 8 * ((l & 7) ^ r8);      // pre-swizzled source col (elems)

    #pragma unroll
    for (int j = 0; j < 2; j++) {
        const int slot = w * 2 + j;
        gload16(Qg + (size_t)(slot * 8 + r8) * LDQ + scol, Qs + slot * 512);
    }

    float m_run[4] = {-1e30f, -1e30f, -1e30f, -1e30f};
    float l_run[4] = {0.f, 0.f, 0.f, 0.f};
    f32x4 acc_o[4] = {};

    for (int kt = 0; kt <= qt; ++kt) {
        __syncthreads();   // prev-iter LDS reads done (iter 0: Q staged)
        #pragma unroll
        for (int j = 0; j < 2; j++) {
            const int slot = w * 2 + j;
            gload16(Kg + (size_t)(kt * 64 + slot * 8 + r8) * LDQ + scol, Ks + slot * 512);
        }
        // V^T: reg-stage with swizzled transpose writes
        unsigned short* vt = reinterpret_cast<unsigned short*>(Vts);
        #pragma unroll
        for (int j = 0; j < 2; j++) {
            const int e = tid + j * 256;
            const int key = e >> 3, f0 = (e & 7) * 8;
            const uint4 raw = *reinterpret_cast<const uint4*>(
                Vg + (size_t)(kt * 64 + key) * LDQ + f0);
            const unsigned int rw[4] = {raw.x, raw.y, raw.z, raw.w};
            #pragma unroll
            for (int e2 = 0; e2 < 8; e2++) {
                const int feat = f0 + e2;
                const int ad = feat * 128 + ((key * 2) ^ ((feat & 7) << 4));
                vt[ad >> 1] = (unsigned short)(rw[e2 >> 1] >> ((e2 & 1) * 16));
            }
        }
        __syncthreads();   // K, V^T staged

        // QK^T -> S [16 q-rows][64 keys] per wave
        f32x4 s4[4] = {};
        #pragma unroll
        for (int kk = 0; kk < 2; kk++) {
            const bfrag aq = *reinterpret_cast<const bfrag*>(
                (const char*)Qs + SWZ(w * 16 + lr, kk * 64 + lg * 16));
            #pragma unroll
            for (int ni = 0; ni < 4; ni++) {
                const bfrag bk = *reinterpret_cast<const bfrag*>(
                    (const char*)Ks + SWZ(ni * 16 + lr, kk * 64 + lg * 16));
                s4[ni] = __builtin_amdgcn_mfma_f32_16x16x32_bf16(aq, bk, s4[ni], 0, 0, 0);
            }
        }
        float p[4][4];
        #pragma unroll
        for (int ni = 0; ni < 4; ni++)
            #pragma unroll
            for (int rg = 0; rg < 4; rg++)
                p[ni][rg] = s4[ni][rg] * 0.125f;
        if (kt == qt) {   // causal mask on diagonal tile
            #pragma unroll
            for (int ni = 0; ni < 4; ni++)
                #pragma unroll
                for (int rg = 0; rg < 4; rg++)
                    if (ni * 16 + lr > w * 16 + lg * 4 + rg) p[ni][rg] = -1e30f;
        }
        float sf[4];
        #pragma unroll
        for (int rg = 0; rg < 4; rg++) {
            float mx = fmaxf(fmaxf(p[0][rg], p[1][rg]), fmaxf(p[2][rg], p[3][rg]));
            #pragma unroll
            for (int o = 1; o < 16; o <<= 1) mx = fmaxf(mx, __shfl_xor(mx, o, 64));
            const float mn = fmaxf(m_run[rg], mx);
            sf[rg] = __expf(m_run[rg] - mn);
            m_run[rg] = mn;
        }
        float rsum[4] = {};
        #pragma unroll
        for (int ni = 0; ni < 4; ni++)
            #pragma unroll
            for (int rg = 0; rg < 4; rg++) {
                const float e = __expf(p[ni][rg] - m_run[rg]);
                p[ni][rg] = e;
                rsum[rg] += e;
            }
        #pragma unroll
        for (int rg = 0; rg < 4; rg++) {
            #pragma unroll
            for (int o = 1; o < 16; o <<= 1) rsum[rg] += __shfl_xor(rsum[rg], o, 64);
            l_run[rg] = l_run[rg] * sf[rg] + rsum[rg];
        }
        #pragma unroll
        for (int di = 0; di < 4; di++)
            #pragma unroll
            for (int rg = 0; rg < 4; rg++)
                acc_o[di][rg] *= sf[rg];
        // P -> bf16 -> per-wave LDS (swizzled), then PV
        unsigned short* pw = reinterpret_cast<unsigned short*>(Ps[w]);
        #pragma unroll
        for (int ni = 0; ni < 4; ni++)
            #pragma unroll
            for (int rg = 0; rg < 4; rg++) {
                const int prow = lg * 4 + rg;
                const int ad = SWZ(prow, (ni * 16 + lr) * 2);
                __hip_bfloat16 pb = __float2bfloat16(p[ni][rg]);
                pw[ad >> 1] = *reinterpret_cast<unsigned short*>(&pb);
            }
        #pragma unroll
        for (int kk = 0; kk < 2; kk++) {
            const bfrag pa = *reinterpret_cast<const bfrag*>(
                (const char*)Ps[w] + SWZ(lr, kk * 64 + lg * 16));
            #pragma unroll
            for (int di = 0; di < 4; di++) {
                const bfrag vb = *reinterpret_cast<const bfrag*>(
                    (const char*)Vts + SWZ(di * 16 + lr, kk * 64 + lg * 16));
                acc_o[di] = __builtin_amdgcn_mfma_f32_16x16x32_bf16(pa, vb, acc_o[di], 0, 0, 0);
            }
        }
    }
    #pragma unroll
    for (int di = 0; di < 4; di++)
        #pragma unroll
        for (int rg = 0; rg < 4; rg++) {
            const int q = qt * 64 + w * 16 + lg * 4 + rg;
            const float v = acc_o[di][rg] / l_run[rg];
            Oc[(size_t)(b * Ss + q) * Dm + h * 64 + di * 16 + lr] = __float2bfloat16(v);
        }
}

extern "C" void kernel_launch(void* const* d_in, const int* in_sizes, int n_in,
                              void* d_out, int out_size, void* d_ws, size_t ws_size,
                              hipStream_t stream) {
    const float* x   = (const float*)d_in[0];
    const float* Wq  = (const float*)d_in[1];
    const float* Wk  = (const float*)d_in[2];
    const float* Wv  = (const float*)d_in[3];
    const float* Wo  = (const float*)d_in[4];
    const float* bo  = (const float*)d_in[5];
    const float* g1  = (const float*)d_in[6];
    const float* be1 = (const float*)d_in[7];
    const float* g2  = (const float*)d_in[8];
    const float* be2 = (const float*)d_in[9];
    const float* W1  = (const float*)d_in[10];
    const float* b1  = (const float*)d_in[11];
    const float* W2  = (const float*)d_in[12];
    const float* b2  = (const float*)d_in[13];
    float* out = (float*)d_out;

    // workspace (bytes): bf16 weights 24MB | n1/concat/n2 16MB | QKV 48MB, h1 64MB
    char* wsb = (char*)d_ws;
    __hip_bfloat16* WqkvT = (__hip_bfloat16*)(wsb);                 // [3072][1024]
    __hip_bfloat16* WoT   = (__hip_bfloat16*)(wsb + 6291456);       // [1024][1024]
    __hip_bfloat16* W1T   = (__hip_bfloat16*)(wsb + 8388608);       // [4096][1024]
    __hip_bfloat16* W2T   = (__hip_bfloat16*)(wsb + 16777216);      // [1024][4096]
    __hip_bfloat16* n1    = (__hip_bfloat16*)(wsb + 25165824);      // [8192][1024]
    __hip_bfloat16* QKV   = (__hip_bfloat16*)(wsb + 41943040);      // [8192][3072]
    __hip_bfloat16* concat = n1;                                    // alias (n1 dead)
    __hip_bfloat16* n2     = n1;                                    // alias (concat dead)
    __hip_bfloat16* h1     = QKV;                                   // alias (QKV dead), [8192][4096]

    // weight transpose+convert
    transpose_cvt<<<dim3(2, 32, 16), 256, 0, stream>>>(Wq, WqkvT,              1024, 64, 65536, 65536);
    transpose_cvt<<<dim3(2, 32, 16), 256, 0, stream>>>(Wk, WqkvT + 1024 * 1024, 1024, 64, 65536, 65536);
    transpose_cvt<<<dim3(2, 32, 16), 256, 0, stream>>>(Wv, WqkvT + 2048 * 1024, 1024, 64, 65536, 65536);
    transpose_cvt<<<dim3(32, 32, 1), 256, 0, stream>>>(Wo, WoT, 1024, 1024, 0, 0);
    transpose_cvt<<<dim3(128, 32, 1), 256, 0, stream>>>(W1, W1T, 1024, 4096, 0, 0);
    transpose_cvt<<<dim3(32, 128, 1), 256, 0, stream>>>(W2, W2T, 4096, 1024, 0, 0);

    ln_bf16<<<NT, 256, 0, stream>>>(x, g1, be1, n1);
    // QKV: M=8192 N=3072 K=1024 -> 64x24 = 1536 blocks
    gemm_db<0><<<1536, 256, 0, stream>>>(n1, Dm, WqkvT, Dm, nullptr, nullptr,
                                         QKV, 3072, 24, Dm);
    attn_mfma<<<NT * Hh / 64, 256, 0, stream>>>(QKV, concat);
    // proj: N=1024 -> 64x8 = 512 blocks
    gemm_db<1><<<512, 256, 0, stream>>>(concat, Dm, WoT, Dm, bo, x,
                                        out, Dm, 8, Dm);
    ln_bf16<<<NT, 256, 0, stream>>>(out, g2, be2, n2);
    // FFN1: N=4096 -> 64x32 = 2048 blocks
    gemm_db<2><<<2048, 256, 0, stream>>>(n2, Dm, W1T, Dm, b1, nullptr,
                                         h1, Ff, 32, Dm);
    // FFN2: M=8192 N=1024 K=4096 -> 512 blocks
    gemm_db<3><<<512, 256, 0, stream>>>(h1, Ff, W2T, Ff, b2, nullptr,
                                        out, Dm, 8, Ff);
}